// Round 9
// baseline (2393.176 us; speedup 1.0000x reference)
//
#include <hip/hip_runtime.h>

// ---------------------------------------------------------------------------
// GCN 2-layer pipeline, bucket-grouped edge-parallel aggregation:
//   h1 = relu(spmm(A, x@W1) + b1); out = relu(spmm(A, h1@W2) + b2)
// Buckets of 128 rows (row>>7). Edges bucket-grouped once (hist->scan->bin);
// NO within-bucket row sort. Aggregation: one block per bucket, LDS fp32
// accumulator [128][D], wave-per-edge ds_add_f32. agg1 fuses gemm2 (MFMA
// from LDS acc @ Wt2 -> sup2). 5 dispatches.
// R5 lesson: no per-row-gather+MFMA serialization (this is edge-parallel).
// ---------------------------------------------------------------------------

typedef unsigned int uint;
typedef unsigned short ushort;
typedef unsigned char uchar;
typedef __attribute__((ext_vector_type(8))) short bf16x8;
typedef __attribute__((ext_vector_type(4))) float f32x4;

#define RPB_SHIFT 7
#define RPB 128          // rows per bucket
#define MAXB 1024        // max buckets (N <= 131072)
#define CH 4096          // edges per bin-block
#define HB 128           // hist blocks

__device__ __forceinline__ ushort f2bf(float f) {   // RNE float->bf16
    uint u = __float_as_uint(f);
    u += 0x7fffu + ((u >> 16) & 1u);
    return (ushort)(u >> 16);
}
__device__ __forceinline__ float bflo(uint p) { return __uint_as_float(p << 16); }
__device__ __forceinline__ float bfhi(uint p) { return __uint_as_float(p & 0xffff0000u); }

__device__ __forceinline__ int wscan(int v, int lane) {
    #pragma unroll
    for (int off = 1; off < 64; off <<= 1) {
        int u = __shfl_up(v, off);
        if (lane >= off) v += u;
    }
    return v;
}

// ---------------- K1: per-block bucket hist partials + Wt prep ----------------
__global__ __launch_bounds__(512) void histprep(const int* __restrict__ row,
                                                int* __restrict__ partial, int E,
                                                const float* __restrict__ W1,
                                                const float* __restrict__ W2,
                                                ushort* __restrict__ Wt1,
                                                ushort* __restrict__ Wt2) {
    int t = threadIdx.x;
    if ((int)blockIdx.x < HB) {
        __shared__ int h[MAXB];
        h[t] = 0; h[t + 512] = 0;
        __syncthreads();
        const int stride = HB * 512;
        for (int e = blockIdx.x * 512 + t; e < E; e += stride)
            atomicAdd(&h[row[e] >> RPB_SHIFT], 1);
        __syncthreads();
        partial[blockIdx.x * MAXB + t]       = h[t];
        partial[blockIdx.x * MAXB + 512 + t] = h[t + 512];
        return;
    }
    int g = ((int)blockIdx.x - HB) * 512 + t;
    if (g < 16384) { int k = g >> 7, n = g & 127; Wt1[n * 128 + k] = f2bf(W1[g]); }
    else if (g < 24576) { int i = g - 16384; int k = i >> 6, n = i & 63; Wt2[n * 128 + k] = f2bf(W2[i]); }
}

// ---------------- K2: sum partials + exclusive bucket scan ----------------
__global__ __launch_bounds__(512) void bucket_scan(const int* __restrict__ partial,
                                                   int* __restrict__ bbase,
                                                   int* __restrict__ bcur, int E) {
    __shared__ int wsum[8];
    int t = threadIdx.x, lane = t & 63, w = t >> 6;
    int c0 = 0, c1 = 0;
    for (int blk = 0; blk < HB; ++blk) {
        int2 p = *(const int2*)(partial + blk * MAXB + 2 * t);
        c0 += p.x; c1 += p.y;
    }
    int s = c0 + c1;
    int v = wscan(s, lane);
    if (lane == 63) wsum[w] = v;
    __syncthreads();
    int woff = 0;
    #pragma unroll
    for (int k = 0; k < 8; ++k) if (k < w) woff += wsum[k];
    int excl = v + woff - s;
    bbase[2 * t] = excl;          bcur[2 * t] = excl;
    bbase[2 * t + 1] = excl + c0; bcur[2 * t + 1] = excl + c0;
    if (t == 0) bbase[MAXB] = E;
}

// ---------------- K3: bin (bucket-group edges) + gemm1, one grid ----------------
// blocks [0,BB): counting-sort CH edges by bucket -> brow8/bcolval bursts.
// blocks [BB,..): sup1[M,128](bf16) = x[M,128](fp32) @ W1 (MFMA, B from L2).
__global__ __launch_bounds__(512) void bin_gemm(
        const int* __restrict__ row, const int* __restrict__ col,
        const float* __restrict__ val, int* __restrict__ bcur,
        uchar* __restrict__ brow8, int2* __restrict__ bcolval, int E, int BB,
        const float* __restrict__ xa, const float* __restrict__ xb, int na,
        const ushort* __restrict__ Wt, ushort* __restrict__ sup1, int M) {
    __shared__ char smem[53248];
    __shared__ int wsum[8];
    int t = threadIdx.x;

    if ((int)blockIdx.x < BB) {
        uchar*  srow8 = (uchar*)smem;                    //  4KB
        int2*   scv   = (int2*)(smem + 4096);            // 32KB
        ushort* sbkt  = (ushort*)(smem + 36864);         //  8KB
        int*    hist  = (int*)(smem + 45056);            //  4KB (reused as g2)
        int*    cur   = (int*)(smem + 49152);            //  4KB
        int lane = t & 63, w = t >> 6;

        hist[t] = 0; hist[t + 512] = 0;
        __syncthreads();
        int e0 = blockIdx.x * CH;
        int rr[8]; int2 rc[8];
        #pragma unroll
        for (int k = 0; k < 8; ++k) {
            int e = e0 + (k << 9) + t;
            if (e < E) {
                rr[k] = row[e];
                rc[k] = make_int2(col[e], __float_as_int(val[e]));
                atomicAdd(&hist[rr[k] >> RPB_SHIFT], 1);
            } else rr[k] = -1;
        }
        __syncthreads();

        int h0 = hist[2 * t], h1 = hist[2 * t + 1];
        int s = h0 + h1;
        int v = wscan(s, lane);
        if (lane == 63) wsum[w] = v;
        __syncthreads();
        int woff = 0, tot = 0;
        #pragma unroll
        for (int k = 0; k < 8; ++k) { int x = wsum[k]; tot += x; if (k < w) woff += x; }
        int lb0 = v + woff - s;
        int lb1 = lb0 + h0;
        cur[2 * t] = lb0; cur[2 * t + 1] = lb1;
        // global reserve; store g2 = gbase - lbase into hist (own slots only)
        if (h0 > 0) hist[2 * t]     = atomicAdd(&bcur[2 * t], h0) - lb0;
        if (h1 > 0) hist[2 * t + 1] = atomicAdd(&bcur[2 * t + 1], h1) - lb1;
        __syncthreads();

        #pragma unroll
        for (int k = 0; k < 8; ++k) {
            if (rr[k] >= 0) {
                int b = rr[k] >> RPB_SHIFT;
                int p = atomicAdd(&cur[b], 1);
                srow8[p] = (uchar)(rr[k] & (RPB - 1));
                sbkt[p]  = (ushort)b;
                scv[p]   = rc[k];
            }
        }
        __syncthreads();

        for (int i = t; i < tot; i += 512) {
            int b = sbkt[i];
            int g = hist[b] + i;
            brow8[g]   = srow8[i];
            bcolval[g] = scv[i];
        }
        return;
    }

    // ---- gemm1: 128 rows/block, 8 waves, B-fragments straight from L2 ----
    ushort (*sX)[136] = (ushort(*)[136])smem;   // 34816B
    int row0 = ((int)blockIdx.x - BB) * 128;
    #pragma unroll
    for (int i = 0; i < 8; ++i) {
        int idx = i * 512 + t;
        int r = idx >> 5, c4 = (idx & 31) << 2;
        int gr = row0 + r;
        float4 v = make_float4(0.f, 0.f, 0.f, 0.f);
        if (gr < M) {
            const float* src = (gr < na) ? (xa + (size_t)gr * 128)
                                         : (xb + (size_t)(gr - na) * 128);
            v = *(const float4*)(src + c4);
        }
        uint2 p;
        p.x = (uint)f2bf(v.x) | ((uint)f2bf(v.y) << 16);
        p.y = (uint)f2bf(v.z) | ((uint)f2bf(v.w) << 16);
        *(uint2*)(&sX[r][c4]) = p;
    }
    __syncthreads();

    int lane = t & 63, w = t >> 6;
    int r0 = w << 4;
    int lrow = lane & 15, lk = (lane >> 4) << 3;
    f32x4 acc[8];
    #pragma unroll
    for (int n = 0; n < 8; ++n) acc[n] = (f32x4){0.f, 0.f, 0.f, 0.f};
    #pragma unroll
    for (int ks = 0; ks < 4; ++ks) {
        bf16x8 a = *(const bf16x8*)(&sX[r0 + lrow][ks * 32 + lk]);
        #pragma unroll
        for (int n = 0; n < 8; ++n) {
            bf16x8 b = *(const bf16x8*)(Wt + (size_t)(n * 16 + lrow) * 128 + ks * 32 + lk);
            acc[n] = __builtin_amdgcn_mfma_f32_16x16x32_bf16(a, b, acc[n], 0, 0, 0);
        }
    }
    // D -> own rows of sX (each wave touches only its 16 rows; no cross-wave hazard)
    #pragma unroll
    for (int n = 0; n < 8; ++n)
        #pragma unroll
        for (int r = 0; r < 4; ++r)
            sX[r0 + ((lane >> 4) << 2) + r][n * 16 + lrow] = f2bf(acc[n][r]);
    __syncthreads();
    #pragma unroll
    for (int i = 0; i < 4; ++i) {
        int idx = i * 512 + t;
        int r = idx >> 4, c8 = (idx & 15) << 3;
        int gr = row0 + r;
        if (gr < M)
            *(uint4*)(sup1 + (size_t)gr * 128 + c8) = *(const uint4*)(&sX[r][c8]);
    }
}

// ---------------- K4: agg1 (LDS fp32 accum) + fused gemm2 -> sup2 ----------------
__global__ __launch_bounds__(1024) void agg1_gemm2(
        const ushort* __restrict__ sup1, const int* __restrict__ bbase,
        const uchar* __restrict__ brow8, const int2* __restrict__ bcolval,
        const float* __restrict__ b1, const ushort* __restrict__ Wt2,
        ushort* __restrict__ sup2, int N) {
    __shared__ float acc[RPB][128];   // 64KB
    int t = threadIdx.x, lane = t & 63, w = t >> 6;   // w: 0..15
    int b = blockIdx.x;

    float4 z = make_float4(0.f, 0.f, 0.f, 0.f);
    #pragma unroll
    for (int i = 0; i < 4; ++i)
        ((float4*)acc)[i * 1024 + t] = z;
    __syncthreads();

    int base = bbase[b], end = bbase[b + 1];
    int cnt = end - base;
    int per = (cnt + 15) >> 4;
    int s0 = base + w * per;
    int s1 = min(s0 + per, end);
    const char* supb = (const char*)sup1;
    uint loff = (uint)lane << 2;

    int e = s0;
    for (; e + 8 <= s1; e += 8) {
        int2 cv[8]; uchar r8[8];
        #pragma unroll
        for (int u = 0; u < 8; ++u) cv[u] = bcolval[e + u];
        #pragma unroll
        for (int u = 0; u < 8; ++u) r8[u] = brow8[e + u];
        uint sv[8];
        #pragma unroll
        for (int u = 0; u < 8; ++u)
            sv[u] = *(const uint*)(supb + ((((uint)cv[u].x) << 8) + loff));
        #pragma unroll
        for (int u = 0; u < 8; ++u) {
            float vv = __int_as_float(cv[u].y);
            atomicAdd(&acc[r8[u]][2 * lane],     vv * bflo(sv[u]));
            atomicAdd(&acc[r8[u]][2 * lane + 1], vv * bfhi(sv[u]));
        }
    }
    for (; e < s1; ++e) {
        int2 cv = bcolval[e];
        uchar r8 = brow8[e];
        uint sv = *(const uint*)(supb + ((((uint)cv.x) << 8) + loff));
        float vv = __int_as_float(cv.y);
        atomicAdd(&acc[r8][2 * lane],     vv * bflo(sv));
        atomicAdd(&acc[r8][2 * lane + 1], vv * bfhi(sv));
    }
    __syncthreads();

    // fused gemm2: 32 16x16 tiles (8 row-tiles x 4 col-tiles), 2 per wave
    int rt = w >> 1, cta = (w & 1) << 1;
    int lrow = lane & 15, lk = (lane >> 4) << 3;
    f32x4 o0 = (f32x4){0.f, 0.f, 0.f, 0.f};
    f32x4 o1 = (f32x4){0.f, 0.f, 0.f, 0.f};
    #pragma unroll
    for (int ks = 0; ks < 4; ++ks) {
        bf16x8 a;
        #pragma unroll
        for (int i = 0; i < 8; ++i) {
            int k = ks * 32 + lk + i;
            float h = fmaxf(acc[rt * 16 + lrow][k] + b1[k], 0.f);
            a[i] = (short)f2bf(h);
        }
        bf16x8 bb0 = *(const bf16x8*)(Wt2 + (size_t)(cta * 16 + lrow) * 128 + ks * 32 + lk);
        bf16x8 bb1 = *(const bf16x8*)(Wt2 + (size_t)((cta + 1) * 16 + lrow) * 128 + ks * 32 + lk);
        o0 = __builtin_amdgcn_mfma_f32_16x16x32_bf16(a, bb0, o0, 0, 0, 0);
        o1 = __builtin_amdgcn_mfma_f32_16x16x32_bf16(a, bb1, o1, 0, 0, 0);
    }
    __syncthreads();   // all A-reads of acc done before overwriting as output tile
    ushort* oT = (ushort*)acc;   // [128][72]
    int orow = rt * 16 + ((lane >> 4) << 2);
    #pragma unroll
    for (int r = 0; r < 4; ++r) {
        oT[(orow + r) * 72 + cta * 16 + lrow]       = f2bf(o0[r]);
        oT[(orow + r) * 72 + (cta + 1) * 16 + lrow] = f2bf(o1[r]);
    }
    __syncthreads();
    int row0 = b << RPB_SHIFT;
    int r = t >> 3, c8 = (t & 7) << 3;
    int gr = row0 + r;
    if (gr < N)
        *(uint4*)(sup2 + (size_t)gr * 64 + c8) = *(const uint4*)(oT + r * 72 + c8);
}

// ---------------- K5: agg2 (LDS fp32 accum) -> out fp32 ----------------
__global__ __launch_bounds__(1024) void agg2(
        const ushort* __restrict__ sup2, const int* __restrict__ bbase,
        const uchar* __restrict__ brow8, const int2* __restrict__ bcolval,
        const float* __restrict__ b2, float* __restrict__ out, int N) {
    __shared__ float acc[RPB][64];   // 32KB
    int t = threadIdx.x, lane = t & 63, w = t >> 6;
    int b = blockIdx.x;

    float4 z = make_float4(0.f, 0.f, 0.f, 0.f);
    #pragma unroll
    for (int i = 0; i < 2; ++i)
        ((float4*)acc)[i * 1024 + t] = z;
    __syncthreads();

    int base = bbase[b], end = bbase[b + 1];
    int cnt = end - base;
    int per = (cnt + 15) >> 4;
    int s0 = base + w * per;
    int s1 = min(s0 + per, end);
    int hl = lane & 31, half = lane >> 5;
    const char* supb = (const char*)sup2;
    uint loff = (uint)hl << 2;

    int e = s0;
    for (; e + 8 <= s1; e += 8) {      // 8 edges; each half-wave handles 4
        int2 cv[4]; uchar r8[4];
        #pragma unroll
        for (int u = 0; u < 4; ++u) {
            int ee = e + 2 * u + half;
            cv[u] = bcolval[ee];
            r8[u] = brow8[ee];
        }
        uint sv[4];
        #pragma unroll
        for (int u = 0; u < 4; ++u)
            sv[u] = *(const uint*)(supb + ((((uint)cv[u].x) << 7) + loff));
        #pragma unroll
        for (int u = 0; u < 4; ++u) {
            float vv = __int_as_float(cv[u].y);
            atomicAdd(&acc[r8[u]][2 * hl],     vv * bflo(sv[u]));
            atomicAdd(&acc[r8[u]][2 * hl + 1], vv * bfhi(sv[u]));
        }
    }
    for (; e + 2 <= s1; e += 2) {
        int ee = e + half;
        int2 cv = bcolval[ee];
        uchar r8 = brow8[ee];
        uint sv = *(const uint*)(supb + ((((uint)cv.x) << 7) + loff));
        float vv = __int_as_float(cv.y);
        atomicAdd(&acc[r8][2 * hl],     vv * bflo(sv));
        atomicAdd(&acc[r8][2 * hl + 1], vv * bfhi(sv));
    }
    if (e < s1 && half == 0) {
        int2 cv = bcolval[e];
        uchar r8 = brow8[e];
        uint sv = *(const uint*)(supb + ((((uint)cv.x) << 7) + loff));
        float vv = __int_as_float(cv.y);
        atomicAdd(&acc[r8][2 * hl],     vv * bflo(sv));
        atomicAdd(&acc[r8][2 * hl + 1], vv * bfhi(sv));
    }
    __syncthreads();

    int row0 = b << RPB_SHIFT;
    #pragma unroll
    for (int i = 0; i < 2; ++i) {
        int idx = i * 1024 + t;
        int r = idx >> 4, c4 = (idx & 15) << 2;
        int gr = row0 + r;
        if (gr < N) {
            float4 a = *(const float4*)(&acc[r][c4]);
            float4 bb = *(const float4*)(b2 + c4);
            float4 o = make_float4(fmaxf(a.x + bb.x, 0.f), fmaxf(a.y + bb.y, 0.f),
                                   fmaxf(a.z + bb.z, 0.f), fmaxf(a.w + bb.w, 0.f));
            *(float4*)(out + (size_t)gr * 64 + c4) = o;
        }
    }
}

// ---------------- launch ----------------

extern "C" void kernel_launch(void* const* d_in, const int* in_sizes, int n_in,
                              void* d_out, int out_size, void* d_ws, size_t ws_size,
                              hipStream_t stream) {
    const int*   ei        = (const int*)d_in[0];     // [2, E]
    const float* vals      = (const float*)d_in[1];   // [E]
    const float* emb_node  = (const float*)d_in[2];   // [NN, 128]
    const float* emb_attri = (const float*)d_in[3];   // [NA, 128]
    const float* W1        = (const float*)d_in[4];   // [128, 128]
    const float* b1        = (const float*)d_in[5];   // [128]
    const float* W2        = (const float*)d_in[6];   // [128, 64]
    const float* b2        = (const float*)d_in[7];   // [64]

    const int E  = in_sizes[1];
    const int NN = in_sizes[2] / 128;
    const int NA = in_sizes[3] / 128;
    const int N  = NN + NA;
    const int nb = (N + RPB - 1) >> RPB_SHIFT;        // <= 1024

    const int* row = ei;
    const int* col = ei + E;

    // Workspace (~62 MiB), all disjoint:
    char*  ws   = (char*)d_ws;
    size_t A    = 512;
    size_t S1   = (((size_t)N * 128 * sizeof(ushort)) + A - 1) / A * A;   // sup1 28.2MB
    size_t S2   = (((size_t)N * 64  * sizeof(ushort)) + A - 1) / A * A;   // sup2 14.1MB
    size_t CVB  = (((size_t)E * sizeof(int2)) + A - 1) / A * A;           // bcolval 16MB
    size_t R8B  = (((size_t)E) + A - 1) / A * A;                          // brow8 2MB

    ushort* sup1    = (ushort*)ws;
    ushort* sup2    = (ushort*)(ws + S1);
    int2*   bcolval = (int2*)(ws + S1 + S2);
    uchar*  brow8   = (uchar*)(ws + S1 + S2 + CVB);
    char*   meta    = ws + S1 + S2 + CVB + R8B;
    int*    bbase   = (int*)meta;                         // MAXB+1 ints
    int*    bcur    = (int*)(meta + 8192);                // MAXB ints
    ushort* Wt1     = (ushort*)(meta + 16384);            // 32KB
    ushort* Wt2     = (ushort*)(meta + 16384 + 32768);    // 16KB
    int*    partial = (int*)(meta + 16384 + 49152);       // HB*MAXB ints = 512KB

    int gblocks = (N + 127) / 128;
    int BB = (E + CH - 1) / CH;

    // 1. bucket-hist partials + Wt prep
    histprep<<<HB + 48, 512, 0, stream>>>(row, partial, E, W1, W2, Wt1, Wt2);
    // 2. sum partials + exclusive scan -> bbase/bcur
    bucket_scan<<<1, 512, 0, stream>>>(partial, bbase, bcur, E);
    // 3. bin (bucket-group edges) + gemm1 overlapped
    bin_gemm<<<BB + gblocks, 512, 0, stream>>>(row, col, vals, bcur, brow8, bcolval,
                                               E, BB, emb_node, emb_attri, NN, Wt1, sup1, N);
    // 4. layer-1 aggregation (LDS accum) + fused gemm2 -> sup2
    agg1_gemm2<<<nb, 1024, 0, stream>>>(sup1, bbase, brow8, bcolval, b1, Wt2, sup2, N);
    // 5. layer-2 aggregation -> out
    agg2<<<nb, 1024, 0, stream>>>(sup2, bbase, brow8, bcolval, b2, (float*)d_out, N);
}

// Round 10
// 280.434 us; speedup vs baseline: 8.5338x; 8.5338x over previous
//
#include <hip/hip_runtime.h>

// ---------------------------------------------------------------------------
// GCN 2-layer pipeline:
//   h1 = relu(spmm(A, x@W1) + b1); out = relu(spmm(A, h1@W2) + b2)
// CSR build: bucket sort (row>>8) -> per-bucket LDS scatter (L2-resident).
// R10 = R8 structure with: bin LDS compacted (26.6KB union, 6 blk/CU),
//       gemm1 B-fragments from L2 (no sW stage), final_scatter @512 thr,
//       brow as uchar local-id (2MB).
// agg128: full wave/row, 16-edge unroll. agg64: quarter-wave, 32 in flight.
// R5/R9 lessons: no gather+MFMA fusion, no LDS-atomic accumulation.
// ---------------------------------------------------------------------------

typedef unsigned int uint;
typedef unsigned short ushort;
typedef unsigned char uchar;
typedef __attribute__((ext_vector_type(8))) short bf16x8;
typedef __attribute__((ext_vector_type(4))) float f32x4;

#define RPB_SHIFT 8
#define RPB 256          // rows per bucket
#define MAXB 512         // max buckets (N <= 131072)
#define CH 2048          // edges per bin-block
#define HB 512           // hist blocks in histprep

__device__ __forceinline__ ushort f2bf(float f) {   // RNE float->bf16
    uint u = __float_as_uint(f);
    u += 0x7fffu + ((u >> 16) & 1u);
    return (ushort)(u >> 16);
}
__device__ __forceinline__ float bflo(uint p) { return __uint_as_float(p << 16); }
__device__ __forceinline__ float bfhi(uint p) { return __uint_as_float(p & 0xffff0000u); }

__device__ __forceinline__ int wscan(int v, int lane) {
    #pragma unroll
    for (int off = 1; off < 64; off <<= 1) {
        int u = __shfl_up(v, off);
        if (lane >= off) v += u;
    }
    return v;
}

// ---------------- K1: per-block bucket hist partials + Wt prep ----------------
__global__ __launch_bounds__(256) void histprep(const int* __restrict__ row,
                                                int* __restrict__ partial, int E,
                                                const float* __restrict__ W1,
                                                const float* __restrict__ W2,
                                                ushort* __restrict__ Wt1,
                                                ushort* __restrict__ Wt2) {
    int t = threadIdx.x;
    if ((int)blockIdx.x < HB) {
        __shared__ int h[MAXB];
        h[t] = 0; h[t + 256] = 0;
        __syncthreads();
        const int stride = HB * 256;
        for (int e = blockIdx.x * 256 + t; e < E; e += stride)
            atomicAdd(&h[row[e] >> RPB_SHIFT], 1);
        __syncthreads();
        partial[blockIdx.x * MAXB + t]       = h[t];
        partial[blockIdx.x * MAXB + 256 + t] = h[t + 256];
        return;
    }
    int g = ((int)blockIdx.x - HB) * 256 + t;
    if (g < 16384) { int k = g >> 7, n = g & 127; Wt1[n * 128 + k] = f2bf(W1[g]); }
    else if (g < 24576) { int i = g - 16384; int k = i >> 6, n = i & 63; Wt2[n * 128 + k] = f2bf(W2[i]); }
}

// ---------------- K2: sum partials + exclusive bucket scan ----------------
__global__ __launch_bounds__(256) void bucket_scan(const int* __restrict__ partial,
                                                   int* __restrict__ bbase,
                                                   int* __restrict__ bcur,
                                                   int* __restrict__ rowptr,
                                                   int nbuckets, int N, int E) {
    __shared__ int wsum[4];
    int t = threadIdx.x, lane = t & 63, w = t >> 6;
    int c0 = 0, c1 = 0;
    #pragma unroll 8
    for (int blk = 0; blk < HB; ++blk) {
        int2 p = *(const int2*)(partial + blk * MAXB + 2 * t);
        c0 += p.x; c1 += p.y;
    }
    int s = c0 + c1;
    int v = wscan(s, lane);
    if (lane == 63) wsum[w] = v;
    __syncthreads();
    int woff = 0;
    #pragma unroll
    for (int k = 0; k < 4; ++k) if (k < w) woff += wsum[k];
    int excl = v + woff - s;
    if (2 * t < nbuckets)     { bbase[2 * t] = excl;          bcur[2 * t] = excl; }
    if (2 * t + 1 < nbuckets) { bbase[2 * t + 1] = excl + c0; bcur[2 * t + 1] = excl + c0; }
    if (t == 0) { bbase[nbuckets] = E; rowptr[N] = E; }
}

// ---------------- K3: bin + gemm1 in one grid ----------------
// blocks [0,BB): counting-sort CH edges by bucket -> brow8/bcolval bursts.
// blocks [BB,..): sup1[M,128](bf16) = x[M,128](fp32) @ W1 (MFMA, B from L2).
// Union LDS 26624B -> 6 blocks/CU.
__global__ __launch_bounds__(256) void bin_gemm(
        const int* __restrict__ row, const int* __restrict__ col,
        const float* __restrict__ val, int* __restrict__ bcur,
        uchar* __restrict__ brow8, int2* __restrict__ bcolval, int E, int BB,
        const float* __restrict__ xa, const float* __restrict__ xb, int na,
        const ushort* __restrict__ Wt, ushort* __restrict__ sup1, int M) {
    __shared__ char smem[26624];
    __shared__ int wsum[4];
    int t = threadIdx.x;

    if ((int)blockIdx.x < BB) {
        uchar*  srow8 = (uchar*)smem;                    //  2KB
        int2*   scv   = (int2*)(smem + 2048);            // 16KB
        ushort* sbkt  = (ushort*)(smem + 18432);         //  4KB
        int*    hist  = (int*)(smem + 22528);            //  2KB (reused as g2)
        int*    cur   = (int*)(smem + 24576);            //  2KB
        int lane = t & 63, w = t >> 6;

        hist[t] = 0; hist[t + 256] = 0;
        __syncthreads();
        int e0 = blockIdx.x * CH;
        int rr[8]; int2 rc[8];
        #pragma unroll
        for (int k = 0; k < 8; ++k) {
            int e = e0 + (k << 8) + t;
            if (e < E) {
                rr[k] = row[e];
                rc[k] = make_int2(col[e], __float_as_int(val[e]));
                atomicAdd(&hist[rr[k] >> RPB_SHIFT], 1);
            } else rr[k] = -1;
        }
        __syncthreads();

        int h0 = hist[2 * t], h1 = hist[2 * t + 1];
        int s = h0 + h1;
        int v = wscan(s, lane);
        if (lane == 63) wsum[w] = v;
        __syncthreads();
        int woff = 0, tot = 0;
        #pragma unroll
        for (int k = 0; k < 4; ++k) { int x = wsum[k]; tot += x; if (k < w) woff += x; }
        int lb0 = v + woff - s;
        int lb1 = lb0 + h0;
        cur[2 * t] = lb0; cur[2 * t + 1] = lb1;
        // global reserve; g2 = gbase - lbase stored in hist (own slots only)
        if (h0 > 0) hist[2 * t]     = atomicAdd(&bcur[2 * t], h0) - lb0;
        if (h1 > 0) hist[2 * t + 1] = atomicAdd(&bcur[2 * t + 1], h1) - lb1;
        __syncthreads();

        #pragma unroll
        for (int k = 0; k < 8; ++k) {
            if (rr[k] >= 0) {
                int b = rr[k] >> RPB_SHIFT;
                int p = atomicAdd(&cur[b], 1);
                srow8[p] = (uchar)(rr[k] & (RPB - 1));
                sbkt[p]  = (ushort)b;
                scv[p]   = rc[k];
            }
        }
        __syncthreads();

        for (int i = t; i < tot; i += 256) {
            int b = sbkt[i];
            int g = hist[b] + i;
            brow8[g]   = srow8[i];
            bcolval[g] = scv[i];
        }
        return;
    }

    // ---- gemm1: 64 rows/block, 4 waves, B-fragments from L2 ----
    ushort (*sX)[136] = (ushort(*)[136])smem;   // 17408B
    int row0 = ((int)blockIdx.x - BB) * 64;
    #pragma unroll
    for (int i = 0; i < 8; ++i) {
        int idx = i * 256 + t;
        int r = idx >> 5, c4 = (idx & 31) << 2;
        int gr = row0 + r;
        float4 v = make_float4(0.f, 0.f, 0.f, 0.f);
        if (gr < M) {
            const float* src = (gr < na) ? (xa + (size_t)gr * 128)
                                         : (xb + (size_t)(gr - na) * 128);
            v = *(const float4*)(src + c4);
        }
        uint2 p;
        p.x = (uint)f2bf(v.x) | ((uint)f2bf(v.y) << 16);
        p.y = (uint)f2bf(v.z) | ((uint)f2bf(v.w) << 16);
        *(uint2*)(&sX[r][c4]) = p;
    }
    __syncthreads();

    int lane = t & 63, w = t >> 6;
    int r0 = w << 4;
    int lrow = lane & 15, lk = (lane >> 4) << 3;
    f32x4 acc[8];
    #pragma unroll
    for (int n = 0; n < 8; ++n) acc[n] = (f32x4){0.f, 0.f, 0.f, 0.f};
    #pragma unroll
    for (int ks = 0; ks < 4; ++ks) {
        bf16x8 a = *(const bf16x8*)(&sX[r0 + lrow][ks * 32 + lk]);
        #pragma unroll
        for (int n = 0; n < 8; ++n) {
            bf16x8 b = *(const bf16x8*)(Wt + (size_t)(n * 16 + lrow) * 128 + ks * 32 + lk);
            acc[n] = __builtin_amdgcn_mfma_f32_16x16x32_bf16(a, b, acc[n], 0, 0, 0);
        }
    }
    __syncthreads();
    #pragma unroll
    for (int n = 0; n < 8; ++n)
        #pragma unroll
        for (int r = 0; r < 4; ++r)
            sX[r0 + ((lane >> 4) << 2) + r][n * 16 + lrow] = f2bf(acc[n][r]);
    __syncthreads();
    #pragma unroll
    for (int i = 0; i < 4; ++i) {
        int idx = i * 256 + t;
        int r = idx >> 4, c8 = (idx & 15) << 3;
        int gr = row0 + r;
        if (gr < M)
            *(uint4*)(sup1 + (size_t)gr * 128 + c8) = *(const uint4*)(&sX[r][c8]);
    }
}

// ---------------- K4: final_scatter (512 threads, uchar rows) ----------------
__global__ __launch_bounds__(512) void final_scatter(
        const int* __restrict__ bbase, const uchar* __restrict__ brow8,
        const int2* __restrict__ bcolval, int* __restrict__ rowptr,
        int2* __restrict__ csr, int N) {
    __shared__ int h[RPB];
    __shared__ int cur[RPB];
    __shared__ int wsum[4];
    int b = blockIdx.x;
    int t = threadIdx.x;
    int lane = t & 63, w = t >> 6;
    int base = bbase[b], end = bbase[b + 1];
    int row0 = b << RPB_SHIFT;

    if (t < RPB) h[t] = 0;
    __syncthreads();
    for (int i = base + t; i < end; i += 512)
        atomicAdd(&h[brow8[i]], 1);
    __syncthreads();

    int a = 0, v = 0;
    if (t < RPB) {
        a = h[t];
        v = wscan(a, lane);
        if (lane == 63) wsum[w] = v;
    }
    __syncthreads();
    if (t < RPB) {
        int woff = 0;
        #pragma unroll
        for (int k = 0; k < 4; ++k) if (k < w) woff += wsum[k];
        int excl = v + woff - a;
        cur[t] = excl;
        int gr = row0 + t;
        if (gr < N) rowptr[gr] = base + excl;
    }
    __syncthreads();

    for (int i = base + t; i < end; i += 512) {
        int r = brow8[i];
        int p = atomicAdd(&cur[r], 1);
        csr[base + p] = bcolval[i];
    }
}

// ---------------- K6: gemm2: sup2[M,64](bf16) = h1[M,128](bf16) @ W2 -------
__global__ __launch_bounds__(256) void gemm_mfma64(
        const ushort* __restrict__ xa, const ushort* __restrict__ Wt,
        ushort* __restrict__ out, int M) {
    __shared__ ushort sX[64][136];
    __shared__ ushort sW[64][136];
    int t = threadIdx.x;
    int row0 = blockIdx.x * 64;

    #pragma unroll
    for (int i = 0; i < 4; ++i) {
        int idx = i * 256 + t;
        int n = idx >> 4, c8 = (idx & 15) << 3;
        *(uint4*)(&sW[n][c8]) = *(const uint4*)(Wt + n * 128 + c8);
    }
    #pragma unroll
    for (int i = 0; i < 4; ++i) {
        int idx = i * 256 + t;
        int r = idx >> 4, c8 = (idx & 15) << 3;
        int gr = row0 + r;
        uint4 v = make_uint4(0, 0, 0, 0);
        if (gr < M) v = *(const uint4*)(xa + (size_t)gr * 128 + c8);
        *(uint4*)(&sX[r][c8]) = v;
    }
    __syncthreads();

    int lane = t & 63, w = t >> 6;
    int r0 = w * 16;
    int lrow = lane & 15, lk = (lane >> 4) << 3;
    f32x4 acc[4];
    #pragma unroll
    for (int n = 0; n < 4; ++n) acc[n] = (f32x4){0.f, 0.f, 0.f, 0.f};

    #pragma unroll
    for (int ks = 0; ks < 4; ++ks) {
        bf16x8 a = *(const bf16x8*)(&sX[r0 + lrow][ks * 32 + lk]);
        #pragma unroll
        for (int n = 0; n < 4; ++n) {
            bf16x8 b = *(const bf16x8*)(&sW[n * 16 + lrow][ks * 32 + lk]);
            acc[n] = __builtin_amdgcn_mfma_f32_16x16x32_bf16(a, b, acc[n], 0, 0, 0);
        }
    }
    __syncthreads();
    #pragma unroll
    for (int n = 0; n < 4; ++n)
        #pragma unroll
        for (int r = 0; r < 4; ++r)
            sX[r0 + ((lane >> 4) << 2) + r][n * 16 + lrow] = f2bf(acc[n][r]);
    __syncthreads();
    #pragma unroll
    for (int i = 0; i < 2; ++i) {
        int idx = i * 256 + t;
        int r = idx >> 3, c8 = (idx & 7) << 3;
        int gr = row0 + r;
        if (gr < M)
            *(uint4*)(out + (size_t)gr * 64 + c8) = *(const uint4*)(&sX[r][c8]);
    }
}

// ---------------- K5: agg128: full wave/row, 16-edge unroll, bf16 out --------
__global__ __launch_bounds__(256) void agg_kernel128(
        const ushort* __restrict__ sup, const int* __restrict__ rowptr,
        const int2* __restrict__ csr, const float* __restrict__ bias,
        ushort* __restrict__ out, int M) {
    int wid = (blockIdx.x * 256 + threadIdx.x) >> 6;
    int lane = threadIdx.x & 63;
    if (wid >= M) return;
    int jb = __builtin_amdgcn_readfirstlane(rowptr[wid]);
    int je = __builtin_amdgcn_readfirstlane(rowptr[wid + 1]);
    const char* supb = (const char*)sup;
    uint loff = (uint)lane << 2;
    float a0x = 0.f, a0y = 0.f, a1x = 0.f, a1y = 0.f;
    float a2x = 0.f, a2y = 0.f, a3x = 0.f, a3y = 0.f;
    int j = jb;
    for (; j + 16 <= je; j += 16) {
        int2 c[16];
        #pragma unroll
        for (int u = 0; u < 16; ++u) c[u] = csr[j + u];
        uint sv[16];
        #pragma unroll
        for (int u = 0; u < 16; ++u)
            sv[u] = *(const uint*)(supb + ((((uint)c[u].x) << 8) | loff));
        #pragma unroll
        for (int u = 0; u < 16; ++u) {
            float v = __int_as_float(c[u].y);
            float lo = bflo(sv[u]), hi = bfhi(sv[u]);
            switch (u & 3) {
                case 0: a0x = fmaf(v, lo, a0x); a0y = fmaf(v, hi, a0y); break;
                case 1: a1x = fmaf(v, lo, a1x); a1y = fmaf(v, hi, a1y); break;
                case 2: a2x = fmaf(v, lo, a2x); a2y = fmaf(v, hi, a2y); break;
                default: a3x = fmaf(v, lo, a3x); a3y = fmaf(v, hi, a3y); break;
            }
        }
    }
    for (; j + 4 <= je; j += 4) {
        int2 c[4];
        #pragma unroll
        for (int u = 0; u < 4; ++u) c[u] = csr[j + u];
        uint sv[4];
        #pragma unroll
        for (int u = 0; u < 4; ++u)
            sv[u] = *(const uint*)(supb + ((((uint)c[u].x) << 8) | loff));
        #pragma unroll
        for (int u = 0; u < 4; ++u) {
            float v = __int_as_float(c[u].y);
            if (u & 1) { a1x = fmaf(v, bflo(sv[u]), a1x); a1y = fmaf(v, bfhi(sv[u]), a1y); }
            else       { a0x = fmaf(v, bflo(sv[u]), a0x); a0y = fmaf(v, bfhi(sv[u]), a0y); }
        }
    }
    for (; j < je; ++j) {
        int2 cc = csr[j];
        uint sv = *(const uint*)(supb + ((((uint)cc.x) << 8) | loff));
        float v = __int_as_float(cc.y);
        a0x = fmaf(v, bflo(sv), a0x); a0y = fmaf(v, bfhi(sv), a0y);
    }
    float2 b = *(const float2*)(bias + (lane << 1));
    float hx = fmaxf(a0x + a1x + a2x + a3x + b.x, 0.f);
    float hy = fmaxf(a0y + a1y + a2y + a3y + b.y, 0.f);
    uint p = (uint)f2bf(hx) | ((uint)f2bf(hy) << 16);
    *(uint*)(out + ((size_t)wid << 7) + (lane << 1)) = p;
}

// ---------------- K7: agg64: quarter-wave per edge, fp32 out ----------------
__global__ __launch_bounds__(256) void agg_kernel64(
        const ushort* __restrict__ sup, const int* __restrict__ rowptr,
        const int2* __restrict__ csr, const float* __restrict__ bias,
        float* __restrict__ out, int M) {
    int wid = (blockIdx.x * 256 + threadIdx.x) >> 6;
    int lane = threadIdx.x & 63;
    if (wid >= M) return;
    int ql = lane & 15, q = lane >> 4;
    int jb = __builtin_amdgcn_readfirstlane(rowptr[wid]);
    int je = __builtin_amdgcn_readfirstlane(rowptr[wid + 1]);
    const char* supb = (const char*)sup;
    uint loff = (uint)ql << 3;
    float s0 = 0.f, s1 = 0.f, s2 = 0.f, s3 = 0.f;
    float t0 = 0.f, t1 = 0.f, t2 = 0.f, t3 = 0.f;
    int j = jb;
    for (; j + 32 <= je; j += 32) {
        int2 c[8];
        #pragma unroll
        for (int u = 0; u < 8; ++u) c[u] = csr[j + 4 * u + q];
        uint2 g[8];
        #pragma unroll
        for (int u = 0; u < 8; ++u)
            g[u] = *(const uint2*)(supb + ((((uint)c[u].x) << 7) | loff));
        #pragma unroll
        for (int u = 0; u < 8; ++u) {
            float v = __int_as_float(c[u].y);
            if (u & 1) {
                t0 = fmaf(v, bflo(g[u].x), t0); t1 = fmaf(v, bfhi(g[u].x), t1);
                t2 = fmaf(v, bflo(g[u].y), t2); t3 = fmaf(v, bfhi(g[u].y), t3);
            } else {
                s0 = fmaf(v, bflo(g[u].x), s0); s1 = fmaf(v, bfhi(g[u].x), s1);
                s2 = fmaf(v, bflo(g[u].y), s2); s3 = fmaf(v, bfhi(g[u].y), s3);
            }
        }
    }
    for (; j + 4 <= je; j += 4) {
        int2 c = csr[j + q];
        uint2 g = *(const uint2*)(supb + ((((uint)c.x) << 7) | loff));
        float v = __int_as_float(c.y);
        s0 = fmaf(v, bflo(g.x), s0); s1 = fmaf(v, bfhi(g.x), s1);
        s2 = fmaf(v, bflo(g.y), s2); s3 = fmaf(v, bfhi(g.y), s3);
    }
    int rem = je - j;
    if (q < rem) {
        int2 c = csr[j + q];
        uint2 g = *(const uint2*)(supb + ((((uint)c.x) << 7) | loff));
        float v = __int_as_float(c.y);
        s0 = fmaf(v, bflo(g.x), s0); s1 = fmaf(v, bfhi(g.x), s1);
        s2 = fmaf(v, bflo(g.y), s2); s3 = fmaf(v, bfhi(g.y), s3);
    }
    s0 += t0; s1 += t1; s2 += t2; s3 += t3;
    s0 += __shfl_xor(s0, 16); s0 += __shfl_xor(s0, 32);
    s1 += __shfl_xor(s1, 16); s1 += __shfl_xor(s1, 32);
    s2 += __shfl_xor(s2, 16); s2 += __shfl_xor(s2, 32);
    s3 += __shfl_xor(s3, 16); s3 += __shfl_xor(s3, 32);
    if (q == 0) {
        float4 b = *(const float4*)(bias + (ql << 2));
        float4 o = make_float4(fmaxf(s0 + b.x, 0.f), fmaxf(s1 + b.y, 0.f),
                               fmaxf(s2 + b.z, 0.f), fmaxf(s3 + b.w, 0.f));
        *(float4*)(out + ((size_t)wid << 6) + (ql << 2)) = o;
    }
}

// ---------------- launch ----------------

extern "C" void kernel_launch(void* const* d_in, const int* in_sizes, int n_in,
                              void* d_out, int out_size, void* d_ws, size_t ws_size,
                              hipStream_t stream) {
    const int*   ei        = (const int*)d_in[0];     // [2, E]
    const float* vals      = (const float*)d_in[1];   // [E]
    const float* emb_node  = (const float*)d_in[2];   // [NN, 128]
    const float* emb_attri = (const float*)d_in[3];   // [NA, 128]
    const float* W1        = (const float*)d_in[4];   // [128, 128]
    const float* b1        = (const float*)d_in[5];   // [128]
    const float* W2        = (const float*)d_in[6];   // [128, 64]
    const float* b2        = (const float*)d_in[7];   // [64]

    const int E  = in_sizes[1];
    const int NN = in_sizes[2] / 128;
    const int NA = in_sizes[3] / 128;
    const int N  = NN + NA;
    const int nbuckets = (N + RPB - 1) >> RPB_SHIFT;   // <= 512

    const int* row = ei;
    const int* col = ei + E;

    // Workspace (~75 MiB). sup reused by both layers; brow8/bcolval alias the
    // h1 slot (dead until agg128 writes it).
    char*  ws   = (char*)d_ws;
    size_t A    = 512;
    size_t Ss   = (((size_t)N * 128 * sizeof(ushort)) + A - 1) / A * A;   // sup bf16
    size_t Sh   = (((size_t)N * 128 * sizeof(ushort)) + A - 1) / A * A;   // h1 bf16 / bin slot
    size_t csrB = (((size_t)E * sizeof(int2))         + A - 1) / A * A;
    size_t rpB  = (((size_t)(N + 1) * sizeof(int))    + A - 1) / A * A;
    size_t cvB  = (((size_t)E * sizeof(int2)) + A - 1) / A * A;

    ushort* sup    = (ushort*)ws;
    ushort* h1     = (ushort*)(ws + Ss);
    int2*   bcolval= (int2*)(ws + Ss);                   // aliases h1 (16MB)
    uchar*  brow8  = (uchar*)(ws + Ss + cvB);            // aliases h1 (+2MB = 18 <= 28MB)
    int2*   csr    = (int2*)(ws + Ss + Sh);
    int*    rowptr = (int*)(ws + Ss + Sh + csrB);
    char*   meta   = ws + Ss + Sh + csrB + rpB;
    int*    bbase  = (int*)meta;                          // 513 ints
    int*    bcur   = (int*)(meta + 2560);                 // 512 ints
    ushort* Wt1    = (ushort*)(meta + 8192);              // 32 KB
    ushort* Wt2    = (ushort*)(meta + 8192 + 32768);      // 16 KB
    int*    partial= (int*)(meta + 57344);                // HB*MAXB ints = 1 MB

    int gblocks = (N + 63) / 64;
    int ablocks = (N + 3) / 4;
    int BB = (E + CH - 1) / CH;

    // 1. hist partials + Wt prep
    histprep<<<HB + 96, 256, 0, stream>>>(row, partial, E, W1, W2, Wt1, Wt2);
    // 2. sum partials + bucket scan
    bucket_scan<<<1, 256, 0, stream>>>(partial, bbase, bcur, rowptr, nbuckets, N, E);
    // 3. bin (26.6KB LDS) + gemm1 (B from L2) overlapped
    bin_gemm<<<BB + gblocks, 256, 0, stream>>>(row, col, vals, bcur, brow8, bcolval,
                                               E, BB, emb_node, emb_attri, NN, Wt1, sup, N);
    // 4. per-bucket row sort -> rowptr + csr
    final_scatter<<<nbuckets, 512, 0, stream>>>(bbase, brow8, bcolval, rowptr, csr, N);
    // 5. layer-1 aggregation
    agg_kernel128<<<ablocks, 256, 0, stream>>>(sup, rowptr, csr, b1, h1, N);
    // 6. layer-2 GEMM
    gemm_mfma64<<<gblocks, 256, 0, stream>>>(h1, Wt2, sup, N);
    // 7. layer-2 aggregation
    agg_kernel64<<<ablocks, 256, 0, stream>>>(sup, rowptr, csr, b2, (float*)d_out, N);
}

// Round 11
// 240.129 us; speedup vs baseline: 9.9662x; 1.1678x over previous
//
#include <hip/hip_runtime.h>

// ---------------------------------------------------------------------------
// GCN 2-layer pipeline:
//   h1 = relu(spmm(A, x@W1) + b1); out = relu(spmm(A, h1@W2) + b2)
// CSR build (atomic-free radix structure):
//   histgemm: per-binblock bucket hist (no atomics) ∥ gemm1 (MFMA, sW staged
//             from W1 with transpose) ∥ Wt2 prep
//   scanA:    column scan of partial -> per-(blk,bucket) offsets + colsum
//   scanB:    bucket bases
//   bin:      LDS counting sort, deterministic burst writes (NO global atomics)
//   final_scatter: per-bucket row sort -> rowptr + csr
// agg128: full wave/row, 16-edge unroll. agg64: quarter-wave, 32 in flight.
// Lessons: R5/R9 no gather+MFMA fusion, no LDS-atomic accum; R10: keep sW
// staged in LDS (L2 B-fragments regress); R8: global reserve atomics = serial.
// ---------------------------------------------------------------------------

typedef unsigned int uint;
typedef unsigned short ushort;
typedef unsigned char uchar;
typedef __attribute__((ext_vector_type(8))) short bf16x8;
typedef __attribute__((ext_vector_type(4))) float f32x4;

#define RPB_SHIFT 8
#define RPB 256          // rows per bucket
#define MAXB 512         // max buckets (N <= 131072)
#define CH 2048          // edges per bin-block

__device__ __forceinline__ ushort f2bf(float f) {   // RNE float->bf16
    uint u = __float_as_uint(f);
    u += 0x7fffu + ((u >> 16) & 1u);
    return (ushort)(u >> 16);
}
__device__ __forceinline__ float bflo(uint p) { return __uint_as_float(p << 16); }
__device__ __forceinline__ float bfhi(uint p) { return __uint_as_float(p & 0xffff0000u); }

__device__ __forceinline__ int wscan(int v, int lane) {
    #pragma unroll
    for (int off = 1; off < 64; off <<= 1) {
        int u = __shfl_up(v, off);
        if (lane >= off) v += u;
    }
    return v;
}

// ---------------- K1: per-binblock hist ∥ gemm1 ∥ Wt2 prep ----------------
// blocks [0,BB):           hist of edges [blk*CH, blk*CH+CH) -> partial[blk][*]
// blocks [BB,BB+gblocks):  sup1[M,128](bf16) = x[M,128](fp32) @ W1 (MFMA)
// blocks [BB+gblocks,+32): Wt2[n][k] = bf16(W2[k][n])
__global__ __launch_bounds__(256) void histgemm(
        const int* __restrict__ row, int* __restrict__ partial, int E, int BB,
        const float* __restrict__ xa, const float* __restrict__ xb, int na,
        const float* __restrict__ W1, ushort* __restrict__ sup1, int M,
        const float* __restrict__ W2, ushort* __restrict__ Wt2, int gblocks) {
    __shared__ char smem[52224];
    int t = threadIdx.x;
    int bid = blockIdx.x;

    if (bid < BB) {
        int* h = (int*)smem;
        h[t] = 0; h[t + 256] = 0;
        __syncthreads();
        int e0 = bid * CH;
        #pragma unroll
        for (int k = 0; k < 8; ++k) {
            int e = e0 + (k << 8) + t;
            if (e < E) atomicAdd(&h[row[e] >> RPB_SHIFT], 1);
        }
        __syncthreads();
        partial[(size_t)bid * MAXB + t]       = h[t];
        partial[(size_t)bid * MAXB + 256 + t] = h[t + 256];
        return;
    }
    if (bid >= BB + gblocks) {
        int g = (bid - BB - gblocks) * 256 + t;
        if (g < 8192) { int k = g >> 6, n = g & 63; Wt2[n * 128 + k] = f2bf(W2[g]); }
        return;
    }

    // ---- gemm1: 64 rows/block, 4 waves, sW staged from W1 (transpose) ----
    ushort (*sX)[136] = (ushort(*)[136])smem;            // 17408B
    ushort (*sW)[136] = (ushort(*)[136])(smem + 17408);  // 34816B
    int row0 = (bid - BB) * 64;

    #pragma unroll
    for (int i = 0; i < 16; ++i) {           // sW[n][k] = bf16(W1[k][n])
        int idx = i * 256 + t;               // 0..4095
        int k = idx >> 5, n4 = (idx & 31) << 2;
        float4 v = *(const float4*)(W1 + k * 128 + n4);
        sW[n4 + 0][k] = f2bf(v.x); sW[n4 + 1][k] = f2bf(v.y);
        sW[n4 + 2][k] = f2bf(v.z); sW[n4 + 3][k] = f2bf(v.w);
    }
    #pragma unroll
    for (int i = 0; i < 8; ++i) {
        int idx = i * 256 + t;
        int r = idx >> 5, c4 = (idx & 31) << 2;
        int gr = row0 + r;
        float4 v = make_float4(0.f, 0.f, 0.f, 0.f);
        if (gr < M) {
            const float* src = (gr < na) ? (xa + (size_t)gr * 128)
                                         : (xb + (size_t)(gr - na) * 128);
            v = *(const float4*)(src + c4);
        }
        uint2 p;
        p.x = (uint)f2bf(v.x) | ((uint)f2bf(v.y) << 16);
        p.y = (uint)f2bf(v.z) | ((uint)f2bf(v.w) << 16);
        *(uint2*)(&sX[r][c4]) = p;
    }
    __syncthreads();

    int lane = t & 63, w = t >> 6;
    int r0 = w << 4;
    int lrow = lane & 15, lk = (lane >> 4) << 3;
    f32x4 acc[8];
    #pragma unroll
    for (int n = 0; n < 8; ++n) acc[n] = (f32x4){0.f, 0.f, 0.f, 0.f};
    #pragma unroll
    for (int ks = 0; ks < 4; ++ks) {
        bf16x8 a = *(const bf16x8*)(&sX[r0 + lrow][ks * 32 + lk]);
        #pragma unroll
        for (int n = 0; n < 8; ++n) {
            bf16x8 b = *(const bf16x8*)(&sW[n * 16 + lrow][ks * 32 + lk]);
            acc[n] = __builtin_amdgcn_mfma_f32_16x16x32_bf16(a, b, acc[n], 0, 0, 0);
        }
    }
    __syncthreads();
    #pragma unroll
    for (int n = 0; n < 8; ++n)
        #pragma unroll
        for (int r = 0; r < 4; ++r)
            sX[r0 + ((lane >> 4) << 2) + r][n * 16 + lrow] = f2bf(acc[n][r]);
    __syncthreads();
    #pragma unroll
    for (int i = 0; i < 4; ++i) {
        int idx = i * 256 + t;
        int r = idx >> 4, c8 = (idx & 15) << 3;
        int gr = row0 + r;
        if (gr < M)
            *(uint4*)(sup1 + (size_t)gr * 128 + c8) = *(const uint4*)(&sX[r][c8]);
    }
}

// ---------------- K2a: column scan of partial (one block per bucket) --------
__global__ __launch_bounds__(256) void scanA(int* __restrict__ partial,
                                             int* __restrict__ colsum, int BB) {
    __shared__ int wsum[4];
    int b = blockIdx.x;
    int t = threadIdx.x, lane = t & 63, w = t >> 6;
    int carry = 0;
    for (int c0 = 0; c0 < BB; c0 += 256) {
        int i = c0 + t;
        int v = (i < BB) ? partial[(size_t)i * MAXB + b] : 0;
        int incl = wscan(v, lane);
        if (lane == 63) wsum[w] = incl;
        __syncthreads();
        int woff = 0, tot = 0;
        #pragma unroll
        for (int k = 0; k < 4; ++k) { int x = wsum[k]; tot += x; if (k < w) woff += x; }
        if (i < BB) partial[(size_t)i * MAXB + b] = incl - v + woff + carry;
        carry += tot;
        __syncthreads();
    }
    if (t == 0) colsum[b] = carry;
}

// ---------------- K2b: bucket bases ----------------
__global__ __launch_bounds__(256) void scanB(const int* __restrict__ colsum,
                                             int* __restrict__ bbase,
                                             int* __restrict__ rowptr, int N, int E) {
    __shared__ int wsum[4];
    int t = threadIdx.x, lane = t & 63, w = t >> 6;
    int c0 = colsum[2 * t], c1 = colsum[2 * t + 1];
    int s = c0 + c1;
    int v = wscan(s, lane);
    if (lane == 63) wsum[w] = v;
    __syncthreads();
    int woff = 0;
    #pragma unroll
    for (int k = 0; k < 4; ++k) if (k < w) woff += wsum[k];
    int excl = v + woff - s;
    bbase[2 * t] = excl;
    bbase[2 * t + 1] = excl + c0;
    if (t == 0) { bbase[MAXB] = E; rowptr[N] = E; }
}

// ---------------- K3: bin — LDS counting sort, NO global atomics ------------
__global__ __launch_bounds__(256) void bin_kernel(
        const int* __restrict__ row, const int* __restrict__ col,
        const float* __restrict__ val, const int* __restrict__ bbase,
        const int* __restrict__ partial,
        uchar* __restrict__ brow8, int2* __restrict__ bcolval, int E) {
    __shared__ uchar srow8[CH];      //  2KB
    __shared__ ushort sbkt[CH];      //  4KB
    __shared__ int2 scv[CH];         // 16KB
    __shared__ int hist[MAXB];       //  2KB (becomes g2)
    __shared__ int cur[MAXB];        //  2KB
    __shared__ int wsum[4];
    int t = threadIdx.x, lane = t & 63, w = t >> 6;
    int blk = blockIdx.x;

    hist[t] = 0; hist[t + 256] = 0;
    __syncthreads();
    int e0 = blk * CH;
    int rr[8]; int2 rc[8];
    #pragma unroll
    for (int k = 0; k < 8; ++k) {
        int e = e0 + (k << 8) + t;
        if (e < E) {
            rr[k] = row[e];
            rc[k] = make_int2(col[e], __float_as_int(val[e]));
            atomicAdd(&hist[rr[k] >> RPB_SHIFT], 1);
        } else rr[k] = -1;
    }
    __syncthreads();

    int h0 = hist[2 * t], h1 = hist[2 * t + 1];
    int s = h0 + h1;
    int v = wscan(s, lane);
    if (lane == 63) wsum[w] = v;
    __syncthreads();
    int woff = 0, tot = 0;
    #pragma unroll
    for (int k = 0; k < 4; ++k) { int x = wsum[k]; tot += x; if (k < w) woff += x; }
    int lb0 = v + woff - s;
    int lb1 = lb0 + h0;
    cur[2 * t] = lb0; cur[2 * t + 1] = lb1;
    // deterministic global base: g2 = bbase[b] + prefix(blk,b) - lbase[b]
    hist[2 * t]     = bbase[2 * t]     + partial[(size_t)blk * MAXB + 2 * t]     - lb0;
    hist[2 * t + 1] = bbase[2 * t + 1] + partial[(size_t)blk * MAXB + 2 * t + 1] - lb1;
    __syncthreads();

    #pragma unroll
    for (int k = 0; k < 8; ++k) {
        if (rr[k] >= 0) {
            int b = rr[k] >> RPB_SHIFT;
            int p = atomicAdd(&cur[b], 1);
            srow8[p] = (uchar)(rr[k] & (RPB - 1));
            sbkt[p]  = (ushort)b;
            scv[p]   = rc[k];
        }
    }
    __syncthreads();

    for (int i = t; i < tot; i += 256) {
        int b = sbkt[i];
        int g = hist[b] + i;
        brow8[g]   = srow8[i];
        bcolval[g] = scv[i];
    }
}

// ---------------- K4: final_scatter (512 threads, uchar rows) ----------------
__global__ __launch_bounds__(512) void final_scatter(
        const int* __restrict__ bbase, const uchar* __restrict__ brow8,
        const int2* __restrict__ bcolval, int* __restrict__ rowptr,
        int2* __restrict__ csr, int N) {
    __shared__ int h[RPB];
    __shared__ int cur[RPB];
    __shared__ int wsum[4];
    int b = blockIdx.x;
    int t = threadIdx.x;
    int lane = t & 63, w = t >> 6;
    int base = bbase[b], end = bbase[b + 1];
    int row0 = b << RPB_SHIFT;

    if (t < RPB) h[t] = 0;
    __syncthreads();
    for (int i = base + t; i < end; i += 512)
        atomicAdd(&h[brow8[i]], 1);
    __syncthreads();

    int a = 0, v = 0;
    if (t < RPB) {
        a = h[t];
        v = wscan(a, lane);
        if (lane == 63) wsum[w] = v;
    }
    __syncthreads();
    if (t < RPB) {
        int woff = 0;
        #pragma unroll
        for (int k = 0; k < 4; ++k) if (k < w) woff += wsum[k];
        int excl = v + woff - a;
        cur[t] = excl;
        int gr = row0 + t;
        if (gr < N) rowptr[gr] = base + excl;
    }
    __syncthreads();

    for (int i = base + t; i < end; i += 512) {
        int r = brow8[i];
        int p = atomicAdd(&cur[r], 1);
        csr[base + p] = bcolval[i];
    }
}

// ---------------- K6: gemm2: sup2[M,64](bf16) = h1[M,128](bf16) @ W2 -------
__global__ __launch_bounds__(256) void gemm_mfma64(
        const ushort* __restrict__ xa, const ushort* __restrict__ Wt,
        ushort* __restrict__ out, int M) {
    __shared__ ushort sX[64][136];
    __shared__ ushort sW[64][136];
    int t = threadIdx.x;
    int row0 = blockIdx.x * 64;

    #pragma unroll
    for (int i = 0; i < 4; ++i) {
        int idx = i * 256 + t;
        int n = idx >> 4, c8 = (idx & 15) << 3;
        *(uint4*)(&sW[n][c8]) = *(const uint4*)(Wt + n * 128 + c8);
    }
    #pragma unroll
    for (int i = 0; i < 4; ++i) {
        int idx = i * 256 + t;
        int r = idx >> 4, c8 = (idx & 15) << 3;
        int gr = row0 + r;
        uint4 v = make_uint4(0, 0, 0, 0);
        if (gr < M) v = *(const uint4*)(xa + (size_t)gr * 128 + c8);
        *(uint4*)(&sX[r][c8]) = v;
    }
    __syncthreads();

    int lane = t & 63, w = t >> 6;
    int r0 = w * 16;
    int lrow = lane & 15, lk = (lane >> 4) << 3;
    f32x4 acc[4];
    #pragma unroll
    for (int n = 0; n < 4; ++n) acc[n] = (f32x4){0.f, 0.f, 0.f, 0.f};

    #pragma unroll
    for (int ks = 0; ks < 4; ++ks) {
        bf16x8 a = *(const bf16x8*)(&sX[r0 + lrow][ks * 32 + lk]);
        #pragma unroll
        for (int n = 0; n < 4; ++n) {
            bf16x8 b = *(const bf16x8*)(&sW[n * 16 + lrow][ks * 32 + lk]);
            acc[n] = __builtin_amdgcn_mfma_f32_16x16x32_bf16(a, b, acc[n], 0, 0, 0);
        }
    }
    __syncthreads();
    #pragma unroll
    for (int n = 0; n < 4; ++n)
        #pragma unroll
        for (int r = 0; r < 4; ++r)
            sX[r0 + ((lane >> 4) << 2) + r][n * 16 + lrow] = f2bf(acc[n][r]);
    __syncthreads();
    #pragma unroll
    for (int i = 0; i < 2; ++i) {
        int idx = i * 256 + t;
        int r = idx >> 3, c8 = (idx & 7) << 3;
        int gr = row0 + r;
        if (gr < M)
            *(uint4*)(out + (size_t)gr * 64 + c8) = *(const uint4*)(&sX[r][c8]);
    }
}

// ---------------- K5: agg128: full wave/row, 16-edge unroll, bf16 out --------
__global__ __launch_bounds__(256) void agg_kernel128(
        const ushort* __restrict__ sup, const int* __restrict__ rowptr,
        const int2* __restrict__ csr, const float* __restrict__ bias,
        ushort* __restrict__ out, int M) {
    int wid = (blockIdx.x * 256 + threadIdx.x) >> 6;
    int lane = threadIdx.x & 63;
    if (wid >= M) return;
    int jb = __builtin_amdgcn_readfirstlane(rowptr[wid]);
    int je = __builtin_amdgcn_readfirstlane(rowptr[wid + 1]);
    const char* supb = (const char*)sup;
    uint loff = (uint)lane << 2;
    float a0x = 0.f, a0y = 0.f, a1x = 0.f, a1y = 0.f;
    float a2x = 0.f, a2y = 0.f, a3x = 0.f, a3y = 0.f;
    int j = jb;
    for (; j + 16 <= je; j += 16) {
        int2 c[16];
        #pragma unroll
        for (int u = 0; u < 16; ++u) c[u] = csr[j + u];
        uint sv[16];
        #pragma unroll
        for (int u = 0; u < 16; ++u)
            sv[u] = *(const uint*)(supb + ((((uint)c[u].x) << 8) | loff));
        #pragma unroll
        for (int u = 0; u < 16; ++u) {
            float v = __int_as_float(c[u].y);
            float lo = bflo(sv[u]), hi = bfhi(sv[u]);
            switch (u & 3) {
                case 0: a0x = fmaf(v, lo, a0x); a0y = fmaf(v, hi, a0y); break;
                case 1: a1x = fmaf(v, lo, a1x); a1y = fmaf(v, hi, a1y); break;
                case 2: a2x = fmaf(v, lo, a2x); a2y = fmaf(v, hi, a2y); break;
                default: a3x = fmaf(v, lo, a3x); a3y = fmaf(v, hi, a3y); break;
            }
        }
    }
    for (; j + 4 <= je; j += 4) {
        int2 c[4];
        #pragma unroll
        for (int u = 0; u < 4; ++u) c[u] = csr[j + u];
        uint sv[4];
        #pragma unroll
        for (int u = 0; u < 4; ++u)
            sv[u] = *(const uint*)(supb + ((((uint)c[u].x) << 8) | loff));
        #pragma unroll
        for (int u = 0; u < 4; ++u) {
            float v = __int_as_float(c[u].y);
            if (u & 1) { a1x = fmaf(v, bflo(sv[u]), a1x); a1y = fmaf(v, bfhi(sv[u]), a1y); }
            else       { a0x = fmaf(v, bflo(sv[u]), a0x); a0y = fmaf(v, bfhi(sv[u]), a0y); }
        }
    }
    for (; j < je; ++j) {
        int2 cc = csr[j];
        uint sv = *(const uint*)(supb + ((((uint)cc.x) << 8) | loff));
        float v = __int_as_float(cc.y);
        a0x = fmaf(v, bflo(sv), a0x); a0y = fmaf(v, bfhi(sv), a0y);
    }
    float2 b = *(const float2*)(bias + (lane << 1));
    float hx = fmaxf(a0x + a1x + a2x + a3x + b.x, 0.f);
    float hy = fmaxf(a0y + a1y + a2y + a3y + b.y, 0.f);
    uint p = (uint)f2bf(hx) | ((uint)f2bf(hy) << 16);
    *(uint*)(out + ((size_t)wid << 7) + (lane << 1)) = p;
}

// ---------------- K7: agg64: quarter-wave per edge, fp32 out ----------------
__global__ __launch_bounds__(256) void agg_kernel64(
        const ushort* __restrict__ sup, const int* __restrict__ rowptr,
        const int2* __restrict__ csr, const float* __restrict__ bias,
        float* __restrict__ out, int M) {
    int wid = (blockIdx.x * 256 + threadIdx.x) >> 6;
    int lane = threadIdx.x & 63;
    if (wid >= M) return;
    int ql = lane & 15, q = lane >> 4;
    int jb = __builtin_amdgcn_readfirstlane(rowptr[wid]);
    int je = __builtin_amdgcn_readfirstlane(rowptr[wid + 1]);
    const char* supb = (const char*)sup;
    uint loff = (uint)ql << 3;
    float s0 = 0.f, s1 = 0.f, s2 = 0.f, s3 = 0.f;
    float t0 = 0.f, t1 = 0.f, t2 = 0.f, t3 = 0.f;
    int j = jb;
    for (; j + 32 <= je; j += 32) {
        int2 c[8];
        #pragma unroll
        for (int u = 0; u < 8; ++u) c[u] = csr[j + 4 * u + q];
        uint2 g[8];
        #pragma unroll
        for (int u = 0; u < 8; ++u)
            g[u] = *(const uint2*)(supb + ((((uint)c[u].x) << 7) | loff));
        #pragma unroll
        for (int u = 0; u < 8; ++u) {
            float v = __int_as_float(c[u].y);
            if (u & 1) {
                t0 = fmaf(v, bflo(g[u].x), t0); t1 = fmaf(v, bfhi(g[u].x), t1);
                t2 = fmaf(v, bflo(g[u].y), t2); t3 = fmaf(v, bfhi(g[u].y), t3);
            } else {
                s0 = fmaf(v, bflo(g[u].x), s0); s1 = fmaf(v, bfhi(g[u].x), s1);
                s2 = fmaf(v, bflo(g[u].y), s2); s3 = fmaf(v, bfhi(g[u].y), s3);
            }
        }
    }
    for (; j + 4 <= je; j += 4) {
        int2 c = csr[j + q];
        uint2 g = *(const uint2*)(supb + ((((uint)c.x) << 7) | loff));
        float v = __int_as_float(c.y);
        s0 = fmaf(v, bflo(g.x), s0); s1 = fmaf(v, bfhi(g.x), s1);
        s2 = fmaf(v, bflo(g.y), s2); s3 = fmaf(v, bfhi(g.y), s3);
    }
    int rem = je - j;
    if (q < rem) {
        int2 c = csr[j + q];
        uint2 g = *(const uint2*)(supb + ((((uint)c.x) << 7) | loff));
        float v = __int_as_float(c.y);
        s0 = fmaf(v, bflo(g.x), s0); s1 = fmaf(v, bfhi(g.x), s1);
        s2 = fmaf(v, bflo(g.y), s2); s3 = fmaf(v, bfhi(g.y), s3);
    }
    s0 += t0; s1 += t1; s2 += t2; s3 += t3;
    s0 += __shfl_xor(s0, 16); s0 += __shfl_xor(s0, 32);
    s1 += __shfl_xor(s1, 16); s1 += __shfl_xor(s1, 32);
    s2 += __shfl_xor(s2, 16); s2 += __shfl_xor(s2, 32);
    s3 += __shfl_xor(s3, 16); s3 += __shfl_xor(s3, 32);
    if (q == 0) {
        float4 b = *(const float4*)(bias + (ql << 2));
        float4 o = make_float4(fmaxf(s0 + b.x, 0.f), fmaxf(s1 + b.y, 0.f),
                               fmaxf(s2 + b.z, 0.f), fmaxf(s3 + b.w, 0.f));
        *(float4*)(out + ((size_t)wid << 6) + (ql << 2)) = o;
    }
}

// ---------------- launch ----------------

extern "C" void kernel_launch(void* const* d_in, const int* in_sizes, int n_in,
                              void* d_out, int out_size, void* d_ws, size_t ws_size,
                              hipStream_t stream) {
    const int*   ei        = (const int*)d_in[0];     // [2, E]
    const float* vals      = (const float*)d_in[1];   // [E]
    const float* emb_node  = (const float*)d_in[2];   // [NN, 128]
    const float* emb_attri = (const float*)d_in[3];   // [NA, 128]
    const float* W1        = (const float*)d_in[4];   // [128, 128]
    const float* b1        = (const float*)d_in[5];   // [128]
    const float* W2        = (const float*)d_in[6];   // [128, 64]
    const float* b2        = (const float*)d_in[7];   // [64]

    const int E  = in_sizes[1];
    const int NN = in_sizes[2] / 128;
    const int NA = in_sizes[3] / 128;
    const int N  = NN + NA;
    const int nbuckets = (N + RPB - 1) >> RPB_SHIFT;   // <= 512

    const int* row = ei;
    const int* col = ei + E;

    int gblocks = (N + 63) / 64;
    int ablocks = (N + 3) / 4;
    int BB = (E + CH - 1) / CH;

    // Workspace (~77 MiB). sup reused by both layers; bcolval/brow8 alias the
    // h1 slot (dead until agg128 writes it).
    char*  ws   = (char*)d_ws;
    size_t A    = 512;
    size_t Ss   = (((size_t)N * 128 * sizeof(ushort)) + A - 1) / A * A;   // sup bf16
    size_t Sh   = (((size_t)N * 128 * sizeof(ushort)) + A - 1) / A * A;   // h1 bf16 / bin slot
    size_t csrB = (((size_t)E * sizeof(int2))         + A - 1) / A * A;
    size_t rpB  = (((size_t)(N + 1) * sizeof(int))    + A - 1) / A * A;
    size_t cvB  = (((size_t)E * sizeof(int2)) + A - 1) / A * A;

    ushort* sup    = (ushort*)ws;
    ushort* h1     = (ushort*)(ws + Ss);
    int2*   bcolval= (int2*)(ws + Ss);                   // aliases h1 (16MB)
    uchar*  brow8  = (uchar*)(ws + Ss + cvB);            // aliases h1 (+2MB <= 28MB)
    int2*   csr    = (int2*)(ws + Ss + Sh);
    int*    rowptr = (int*)(ws + Ss + Sh + csrB);
    char*   meta   = ws + Ss + Sh + csrB + rpB;
    int*    bbase  = (int*)meta;                          // 513 ints
    int*    colsum = (int*)(meta + 2560);                 // 512 ints
    ushort* Wt2    = (ushort*)(meta + 5120);              // 16 KB
    int*    partial= (int*)(meta + 5120 + 16384 + 512);   // BB*MAXB ints (~2MB)

    // 1. per-binblock hist + gemm1 + Wt2 prep (one grid, independent blocks)
    histgemm<<<BB + gblocks + 32, 256, 0, stream>>>(row, partial, E, BB,
                                                    emb_node, emb_attri, NN,
                                                    W1, sup, N, W2, Wt2, gblocks);
    // 2a. column scan: per-(blk,bucket) offsets + colsum
    scanA<<<MAXB, 256, 0, stream>>>(partial, colsum, BB);
    // 2b. bucket bases
    scanB<<<1, 256, 0, stream>>>(colsum, bbase, rowptr, N, E);
    // 3. bin: LDS counting sort, deterministic writes, no atomics
    bin_kernel<<<BB, 256, 0, stream>>>(row, col, vals, bbase, partial,
                                       brow8, bcolval, E);
    // 4. per-bucket row sort -> rowptr + csr
    final_scatter<<<nbuckets, 512, 0, stream>>>(bbase, brow8, bcolval, rowptr, csr, N);
    // 5. layer-1 aggregation
    agg_kernel128<<<ablocks, 256, 0, stream>>>(sup, rowptr, csr, b1, h1, N);
    // 6. layer-2 GEMM
    gemm_mfma64<<<gblocks, 256, 0, stream>>>(h1, Wt2, sup, N);
    // 7. layer-2 aggregation
    agg_kernel64<<<ablocks, 256, 0, stream>>>(sup, rowptr, csr, b2, (float*)d_out, N);
}

// Round 12
// 214.843 us; speedup vs baseline: 11.1392x; 1.1177x over previous
//
#include <hip/hip_runtime.h>

// ---------------------------------------------------------------------------
// GCN 2-layer pipeline:
//   h1 = relu(spmm(A, x@W1) + b1); out = relu(spmm(A, h1@W2) + b2)
// CSR build (atomic-free radix structure):
//   histgemm: per-binblock bucket hist ∥ gemm1 (MFMA) ∥ Wt2 prep
//   scanA/scanB: column scan -> deterministic bin offsets
//   bin: LDS counting sort, no global atomics
//   final_scatter: per-bucket row sort -> rowptr + csr
// agg128: full wave/row, 2 cols/lane, 16-edge unroll.
// agg64 (R12): 4 rows/wave, quarter-wave per ROW (16 lanes x 4 cols),
//   8-edge unroll -> unroll actually triggers at mean degree 18.
// Lessons: R5/R9 no gather+MFMA fusion / LDS-atomic accum; R10 keep sW in
// LDS; R8 global reserve atomics serialize; R11 deep unrolls must match the
// actual degree distribution.
// ---------------------------------------------------------------------------

typedef unsigned int uint;
typedef unsigned short ushort;
typedef unsigned char uchar;
typedef __attribute__((ext_vector_type(8))) short bf16x8;
typedef __attribute__((ext_vector_type(4))) float f32x4;

#define RPB_SHIFT 8
#define RPB 256          // rows per bucket
#define MAXB 512         // max buckets (N <= 131072)
#define CH 2048          // edges per bin-block

__device__ __forceinline__ ushort f2bf(float f) {   // RNE float->bf16
    uint u = __float_as_uint(f);
    u += 0x7fffu + ((u >> 16) & 1u);
    return (ushort)(u >> 16);
}
__device__ __forceinline__ float bflo(uint p) { return __uint_as_float(p << 16); }
__device__ __forceinline__ float bfhi(uint p) { return __uint_as_float(p & 0xffff0000u); }

__device__ __forceinline__ int wscan(int v, int lane) {
    #pragma unroll
    for (int off = 1; off < 64; off <<= 1) {
        int u = __shfl_up(v, off);
        if (lane >= off) v += u;
    }
    return v;
}

// ---------------- K1: per-binblock hist ∥ gemm1 ∥ Wt2 prep ----------------
__global__ __launch_bounds__(256) void histgemm(
        const int* __restrict__ row, int* __restrict__ partial, int E, int BB,
        const float* __restrict__ xa, const float* __restrict__ xb, int na,
        const float* __restrict__ W1, ushort* __restrict__ sup1, int M,
        const float* __restrict__ W2, ushort* __restrict__ Wt2, int gblocks) {
    __shared__ char smem[52224];
    int t = threadIdx.x;
    int bid = blockIdx.x;

    if (bid < BB) {
        int* h = (int*)smem;
        h[t] = 0; h[t + 256] = 0;
        __syncthreads();
        int e0 = bid * CH;
        #pragma unroll
        for (int k = 0; k < 8; ++k) {
            int e = e0 + (k << 8) + t;
            if (e < E) atomicAdd(&h[row[e] >> RPB_SHIFT], 1);
        }
        __syncthreads();
        partial[(size_t)bid * MAXB + t]       = h[t];
        partial[(size_t)bid * MAXB + 256 + t] = h[t + 256];
        return;
    }
    if (bid >= BB + gblocks) {
        int g = (bid - BB - gblocks) * 256 + t;
        if (g < 8192) { int k = g >> 6, n = g & 63; Wt2[n * 128 + k] = f2bf(W2[g]); }
        return;
    }

    // ---- gemm1: 64 rows/block, 4 waves, sW staged from W1 (transpose) ----
    ushort (*sX)[136] = (ushort(*)[136])smem;            // 17408B
    ushort (*sW)[136] = (ushort(*)[136])(smem + 17408);  // 34816B
    int row0 = (bid - BB) * 64;

    #pragma unroll
    for (int i = 0; i < 16; ++i) {           // sW[n][k] = bf16(W1[k][n])
        int idx = i * 256 + t;               // 0..4095
        int k = idx >> 5, n4 = (idx & 31) << 2;
        float4 v = *(const float4*)(W1 + k * 128 + n4);
        sW[n4 + 0][k] = f2bf(v.x); sW[n4 + 1][k] = f2bf(v.y);
        sW[n4 + 2][k] = f2bf(v.z); sW[n4 + 3][k] = f2bf(v.w);
    }
    #pragma unroll
    for (int i = 0; i < 8; ++i) {
        int idx = i * 256 + t;
        int r = idx >> 5, c4 = (idx & 31) << 2;
        int gr = row0 + r;
        float4 v = make_float4(0.f, 0.f, 0.f, 0.f);
        if (gr < M) {
            const float* src = (gr < na) ? (xa + (size_t)gr * 128)
                                         : (xb + (size_t)(gr - na) * 128);
            v = *(const float4*)(src + c4);
        }
        uint2 p;
        p.x = (uint)f2bf(v.x) | ((uint)f2bf(v.y) << 16);
        p.y = (uint)f2bf(v.z) | ((uint)f2bf(v.w) << 16);
        *(uint2*)(&sX[r][c4]) = p;
    }
    __syncthreads();

    int lane = t & 63, w = t >> 6;
    int r0 = w << 4;
    int lrow = lane & 15, lk = (lane >> 4) << 3;
    f32x4 acc[8];
    #pragma unroll
    for (int n = 0; n < 8; ++n) acc[n] = (f32x4){0.f, 0.f, 0.f, 0.f};
    #pragma unroll
    for (int ks = 0; ks < 4; ++ks) {
        bf16x8 a = *(const bf16x8*)(&sX[r0 + lrow][ks * 32 + lk]);
        #pragma unroll
        for (int n = 0; n < 8; ++n) {
            bf16x8 b = *(const bf16x8*)(&sW[n * 16 + lrow][ks * 32 + lk]);
            acc[n] = __builtin_amdgcn_mfma_f32_16x16x32_bf16(a, b, acc[n], 0, 0, 0);
        }
    }
    __syncthreads();
    #pragma unroll
    for (int n = 0; n < 8; ++n)
        #pragma unroll
        for (int r = 0; r < 4; ++r)
            sX[r0 + ((lane >> 4) << 2) + r][n * 16 + lrow] = f2bf(acc[n][r]);
    __syncthreads();
    #pragma unroll
    for (int i = 0; i < 4; ++i) {
        int idx = i * 256 + t;
        int r = idx >> 4, c8 = (idx & 15) << 3;
        int gr = row0 + r;
        if (gr < M)
            *(uint4*)(sup1 + (size_t)gr * 128 + c8) = *(const uint4*)(&sX[r][c8]);
    }
}

// ---------------- K2a: column scan of partial (one block per bucket) --------
__global__ __launch_bounds__(256) void scanA(int* __restrict__ partial,
                                             int* __restrict__ colsum, int BB) {
    __shared__ int wsum[4];
    int b = blockIdx.x;
    int t = threadIdx.x, lane = t & 63, w = t >> 6;
    int carry = 0;
    for (int c0 = 0; c0 < BB; c0 += 256) {
        int i = c0 + t;
        int v = (i < BB) ? partial[(size_t)i * MAXB + b] : 0;
        int incl = wscan(v, lane);
        if (lane == 63) wsum[w] = incl;
        __syncthreads();
        int woff = 0, tot = 0;
        #pragma unroll
        for (int k = 0; k < 4; ++k) { int x = wsum[k]; tot += x; if (k < w) woff += x; }
        if (i < BB) partial[(size_t)i * MAXB + b] = incl - v + woff + carry;
        carry += tot;
        __syncthreads();
    }
    if (t == 0) colsum[b] = carry;
}

// ---------------- K2b: bucket bases ----------------
__global__ __launch_bounds__(256) void scanB(const int* __restrict__ colsum,
                                             int* __restrict__ bbase,
                                             int* __restrict__ rowptr, int N, int E) {
    __shared__ int wsum[4];
    int t = threadIdx.x, lane = t & 63, w = t >> 6;
    int c0 = colsum[2 * t], c1 = colsum[2 * t + 1];
    int s = c0 + c1;
    int v = wscan(s, lane);
    if (lane == 63) wsum[w] = v;
    __syncthreads();
    int woff = 0;
    #pragma unroll
    for (int k = 0; k < 4; ++k) if (k < w) woff += wsum[k];
    int excl = v + woff - s;
    bbase[2 * t] = excl;
    bbase[2 * t + 1] = excl + c0;
    if (t == 0) { bbase[MAXB] = E; rowptr[N] = E; }
}

// ---------------- K3: bin — LDS counting sort, NO global atomics ------------
__global__ __launch_bounds__(256) void bin_kernel(
        const int* __restrict__ row, const int* __restrict__ col,
        const float* __restrict__ val, const int* __restrict__ bbase,
        const int* __restrict__ partial,
        uchar* __restrict__ brow8, int2* __restrict__ bcolval, int E) {
    __shared__ uchar srow8[CH];      //  2KB
    __shared__ ushort sbkt[CH];      //  4KB
    __shared__ int2 scv[CH];         // 16KB
    __shared__ int hist[MAXB];       //  2KB (becomes g2)
    __shared__ int cur[MAXB];        //  2KB
    __shared__ int wsum[4];
    int t = threadIdx.x, lane = t & 63, w = t >> 6;
    int blk = blockIdx.x;

    hist[t] = 0; hist[t + 256] = 0;
    __syncthreads();
    int e0 = blk * CH;
    int rr[8]; int2 rc[8];
    #pragma unroll
    for (int k = 0; k < 8; ++k) {
        int e = e0 + (k << 8) + t;
        if (e < E) {
            rr[k] = row[e];
            rc[k] = make_int2(col[e], __float_as_int(val[e]));
            atomicAdd(&hist[rr[k] >> RPB_SHIFT], 1);
        } else rr[k] = -1;
    }
    __syncthreads();

    int h0 = hist[2 * t], h1 = hist[2 * t + 1];
    int s = h0 + h1;
    int v = wscan(s, lane);
    if (lane == 63) wsum[w] = v;
    __syncthreads();
    int woff = 0, tot = 0;
    #pragma unroll
    for (int k = 0; k < 4; ++k) { int x = wsum[k]; tot += x; if (k < w) woff += x; }
    int lb0 = v + woff - s;
    int lb1 = lb0 + h0;
    cur[2 * t] = lb0; cur[2 * t + 1] = lb1;
    hist[2 * t]     = bbase[2 * t]     + partial[(size_t)blk * MAXB + 2 * t]     - lb0;
    hist[2 * t + 1] = bbase[2 * t + 1] + partial[(size_t)blk * MAXB + 2 * t + 1] - lb1;
    __syncthreads();

    #pragma unroll
    for (int k = 0; k < 8; ++k) {
        if (rr[k] >= 0) {
            int b = rr[k] >> RPB_SHIFT;
            int p = atomicAdd(&cur[b], 1);
            srow8[p] = (uchar)(rr[k] & (RPB - 1));
            sbkt[p]  = (ushort)b;
            scv[p]   = rc[k];
        }
    }
    __syncthreads();

    for (int i = t; i < tot; i += 256) {
        int b = sbkt[i];
        int g = hist[b] + i;
        brow8[g]   = srow8[i];
        bcolval[g] = scv[i];
    }
}

// ---------------- K4: final_scatter (512 threads, uchar rows) ----------------
__global__ __launch_bounds__(512) void final_scatter(
        const int* __restrict__ bbase, const uchar* __restrict__ brow8,
        const int2* __restrict__ bcolval, int* __restrict__ rowptr,
        int2* __restrict__ csr, int N) {
    __shared__ int h[RPB];
    __shared__ int cur[RPB];
    __shared__ int wsum[4];
    int b = blockIdx.x;
    int t = threadIdx.x;
    int lane = t & 63, w = t >> 6;
    int base = bbase[b], end = bbase[b + 1];
    int row0 = b << RPB_SHIFT;

    if (t < RPB) h[t] = 0;
    __syncthreads();
    for (int i = base + t; i < end; i += 512)
        atomicAdd(&h[brow8[i]], 1);
    __syncthreads();

    int a = 0, v = 0;
    if (t < RPB) {
        a = h[t];
        v = wscan(a, lane);
        if (lane == 63) wsum[w] = v;
    }
    __syncthreads();
    if (t < RPB) {
        int woff = 0;
        #pragma unroll
        for (int k = 0; k < 4; ++k) if (k < w) woff += wsum[k];
        int excl = v + woff - a;
        cur[t] = excl;
        int gr = row0 + t;
        if (gr < N) rowptr[gr] = base + excl;
    }
    __syncthreads();

    for (int i = base + t; i < end; i += 512) {
        int r = brow8[i];
        int p = atomicAdd(&cur[r], 1);
        csr[base + p] = bcolval[i];
    }
}

// ---------------- K6: gemm2: sup2[M,64](bf16) = h1[M,128](bf16) @ W2 -------
__global__ __launch_bounds__(256) void gemm_mfma64(
        const ushort* __restrict__ xa, const ushort* __restrict__ Wt,
        ushort* __restrict__ out, int M) {
    __shared__ ushort sX[64][136];
    __shared__ ushort sW[64][136];
    int t = threadIdx.x;
    int row0 = blockIdx.x * 64;

    #pragma unroll
    for (int i = 0; i < 4; ++i) {
        int idx = i * 256 + t;
        int n = idx >> 4, c8 = (idx & 15) << 3;
        *(uint4*)(&sW[n][c8]) = *(const uint4*)(Wt + n * 128 + c8);
    }
    #pragma unroll
    for (int i = 0; i < 4; ++i) {
        int idx = i * 256 + t;
        int r = idx >> 4, c8 = (idx & 15) << 3;
        int gr = row0 + r;
        uint4 v = make_uint4(0, 0, 0, 0);
        if (gr < M) v = *(const uint4*)(xa + (size_t)gr * 128 + c8);
        *(uint4*)(&sX[r][c8]) = v;
    }
    __syncthreads();

    int lane = t & 63, w = t >> 6;
    int r0 = w * 16;
    int lrow = lane & 15, lk = (lane >> 4) << 3;
    f32x4 acc[4];
    #pragma unroll
    for (int n = 0; n < 4; ++n) acc[n] = (f32x4){0.f, 0.f, 0.f, 0.f};

    #pragma unroll
    for (int ks = 0; ks < 4; ++ks) {
        bf16x8 a = *(const bf16x8*)(&sX[r0 + lrow][ks * 32 + lk]);
        #pragma unroll
        for (int n = 0; n < 4; ++n) {
            bf16x8 b = *(const bf16x8*)(&sW[n * 16 + lrow][ks * 32 + lk]);
            acc[n] = __builtin_amdgcn_mfma_f32_16x16x32_bf16(a, b, acc[n], 0, 0, 0);
        }
    }
    __syncthreads();
    #pragma unroll
    for (int n = 0; n < 4; ++n)
        #pragma unroll
        for (int r = 0; r < 4; ++r)
            sX[r0 + ((lane >> 4) << 2) + r][n * 16 + lrow] = f2bf(acc[n][r]);
    __syncthreads();
    #pragma unroll
    for (int i = 0; i < 2; ++i) {
        int idx = i * 256 + t;
        int r = idx >> 3, c8 = (idx & 7) << 3;
        int gr = row0 + r;
        if (gr < M)
            *(uint4*)(out + (size_t)gr * 64 + c8) = *(const uint4*)(&sX[r][c8]);
    }
}

// ---------------- K5: agg128: full wave/row, 16-edge unroll, bf16 out --------
__global__ __launch_bounds__(256) void agg_kernel128(
        const ushort* __restrict__ sup, const int* __restrict__ rowptr,
        const int2* __restrict__ csr, const float* __restrict__ bias,
        ushort* __restrict__ out, int M) {
    int wid = (blockIdx.x * 256 + threadIdx.x) >> 6;
    int lane = threadIdx.x & 63;
    if (wid >= M) return;
    int jb = __builtin_amdgcn_readfirstlane(rowptr[wid]);
    int je = __builtin_amdgcn_readfirstlane(rowptr[wid + 1]);
    const char* supb = (const char*)sup;
    uint loff = (uint)lane << 2;
    float a0x = 0.f, a0y = 0.f, a1x = 0.f, a1y = 0.f;
    float a2x = 0.f, a2y = 0.f, a3x = 0.f, a3y = 0.f;
    int j = jb;
    for (; j + 16 <= je; j += 16) {
        int2 c[16];
        #pragma unroll
        for (int u = 0; u < 16; ++u) c[u] = csr[j + u];
        uint sv[16];
        #pragma unroll
        for (int u = 0; u < 16; ++u)
            sv[u] = *(const uint*)(supb + ((((uint)c[u].x) << 8) | loff));
        #pragma unroll
        for (int u = 0; u < 16; ++u) {
            float v = __int_as_float(c[u].y);
            float lo = bflo(sv[u]), hi = bfhi(sv[u]);
            switch (u & 3) {
                case 0: a0x = fmaf(v, lo, a0x); a0y = fmaf(v, hi, a0y); break;
                case 1: a1x = fmaf(v, lo, a1x); a1y = fmaf(v, hi, a1y); break;
                case 2: a2x = fmaf(v, lo, a2x); a2y = fmaf(v, hi, a2y); break;
                default: a3x = fmaf(v, lo, a3x); a3y = fmaf(v, hi, a3y); break;
            }
        }
    }
    for (; j + 4 <= je; j += 4) {
        int2 c[4];
        #pragma unroll
        for (int u = 0; u < 4; ++u) c[u] = csr[j + u];
        uint sv[4];
        #pragma unroll
        for (int u = 0; u < 4; ++u)
            sv[u] = *(const uint*)(supb + ((((uint)c[u].x) << 8) | loff));
        #pragma unroll
        for (int u = 0; u < 4; ++u) {
            float v = __int_as_float(c[u].y);
            if (u & 1) { a1x = fmaf(v, bflo(sv[u]), a1x); a1y = fmaf(v, bfhi(sv[u]), a1y); }
            else       { a0x = fmaf(v, bflo(sv[u]), a0x); a0y = fmaf(v, bfhi(sv[u]), a0y); }
        }
    }
    for (; j < je; ++j) {
        int2 cc = csr[j];
        uint sv = *(const uint*)(supb + ((((uint)cc.x) << 8) | loff));
        float v = __int_as_float(cc.y);
        a0x = fmaf(v, bflo(sv), a0x); a0y = fmaf(v, bfhi(sv), a0y);
    }
    float2 b = *(const float2*)(bias + (lane << 1));
    float hx = fmaxf(a0x + a1x + a2x + a3x + b.x, 0.f);
    float hy = fmaxf(a0y + a1y + a2y + a3y + b.y, 0.f);
    uint p = (uint)f2bf(hx) | ((uint)f2bf(hy) << 16);
    *(uint*)(out + ((size_t)wid << 7) + (lane << 1)) = p;
}

// ---------------- K7: agg64: 4 rows/wave, quarter-wave per ROW ----------------
// Quarter (16 lanes) owns a full 64-col row: lane ql covers cols 4ql..4ql+3
// (uint2 = 4 bf16). 8-edge unroll -> 8 gathers in flight per quarter
// (32/wave). No cross-lane reduce; float4 coalesced store.
__global__ __launch_bounds__(256) void agg_kernel64(
        const ushort* __restrict__ sup, const int* __restrict__ rowptr,
        const int2* __restrict__ csr, const float* __restrict__ bias,
        float* __restrict__ out, int M) {
    int t = threadIdx.x;
    int lane = t & 63, wv = t >> 6;
    int q = lane >> 4, ql = lane & 15;
    int wid = blockIdx.x * 16 + wv * 4 + q;   // 16 rows per block
    if (wid >= M) return;
    int jb = rowptr[wid], je = rowptr[wid + 1];
    const char* supb = (const char*)sup;
    uint loff = (uint)ql << 3;
    float s0 = 0.f, s1 = 0.f, s2 = 0.f, s3 = 0.f;
    float t0 = 0.f, t1 = 0.f, t2 = 0.f, t3 = 0.f;
    int j = jb;
    for (; j + 8 <= je; j += 8) {
        int2 c[8];
        #pragma unroll
        for (int u = 0; u < 8; ++u) c[u] = csr[j + u];
        uint2 g[8];
        #pragma unroll
        for (int u = 0; u < 8; ++u)
            g[u] = *(const uint2*)(supb + ((((uint)c[u].x) << 7) | loff));
        #pragma unroll
        for (int u = 0; u < 8; ++u) {
            float v = __int_as_float(c[u].y);
            if (u & 1) {
                t0 = fmaf(v, bflo(g[u].x), t0); t1 = fmaf(v, bfhi(g[u].x), t1);
                t2 = fmaf(v, bflo(g[u].y), t2); t3 = fmaf(v, bfhi(g[u].y), t3);
            } else {
                s0 = fmaf(v, bflo(g[u].x), s0); s1 = fmaf(v, bfhi(g[u].x), s1);
                s2 = fmaf(v, bflo(g[u].y), s2); s3 = fmaf(v, bfhi(g[u].y), s3);
            }
        }
    }
    for (; j < je; ++j) {
        int2 c = csr[j];
        uint2 g = *(const uint2*)(supb + ((((uint)c.x) << 7) | loff));
        float v = __int_as_float(c.y);
        s0 = fmaf(v, bflo(g.x), s0); s1 = fmaf(v, bfhi(g.x), s1);
        s2 = fmaf(v, bflo(g.y), s2); s3 = fmaf(v, bfhi(g.y), s3);
    }
    s0 += t0; s1 += t1; s2 += t2; s3 += t3;
    float4 b = *(const float4*)(bias + (ql << 2));
    float4 o = make_float4(fmaxf(s0 + b.x, 0.f), fmaxf(s1 + b.y, 0.f),
                           fmaxf(s2 + b.z, 0.f), fmaxf(s3 + b.w, 0.f));
    *(float4*)(out + ((size_t)wid << 6) + (ql << 2)) = o;
}

// ---------------- launch ----------------

extern "C" void kernel_launch(void* const* d_in, const int* in_sizes, int n_in,
                              void* d_out, int out_size, void* d_ws, size_t ws_size,
                              hipStream_t stream) {
    const int*   ei        = (const int*)d_in[0];     // [2, E]
    const float* vals      = (const float*)d_in[1];   // [E]
    const float* emb_node  = (const float*)d_in[2];   // [NN, 128]
    const float* emb_attri = (const float*)d_in[3];   // [NA, 128]
    const float* W1        = (const float*)d_in[4];   // [128, 128]
    const float* b1        = (const float*)d_in[5];   // [128]
    const float* W2        = (const float*)d_in[6];   // [128, 64]
    const float* b2        = (const float*)d_in[7];   // [64]

    const int E  = in_sizes[1];
    const int NN = in_sizes[2] / 128;
    const int NA = in_sizes[3] / 128;
    const int N  = NN + NA;
    const int nbuckets = (N + RPB - 1) >> RPB_SHIFT;   // <= 512

    const int* row = ei;
    const int* col = ei + E;

    int gblocks = (N + 63) / 64;
    int ablocks = (N + 3) / 4;
    int BB = (E + CH - 1) / CH;

    // Workspace (~77 MiB). sup reused by both layers; bcolval/brow8 alias the
    // h1 slot (dead until agg128 writes it).
    char*  ws   = (char*)d_ws;
    size_t A    = 512;
    size_t Ss   = (((size_t)N * 128 * sizeof(ushort)) + A - 1) / A * A;   // sup bf16
    size_t Sh   = (((size_t)N * 128 * sizeof(ushort)) + A - 1) / A * A;   // h1 bf16 / bin slot
    size_t csrB = (((size_t)E * sizeof(int2))         + A - 1) / A * A;
    size_t rpB  = (((size_t)(N + 1) * sizeof(int))    + A - 1) / A * A;
    size_t cvB  = (((size_t)E * sizeof(int2)) + A - 1) / A * A;

    ushort* sup    = (ushort*)ws;
    ushort* h1     = (ushort*)(ws + Ss);
    int2*   bcolval= (int2*)(ws + Ss);                   // aliases h1 (16MB)
    uchar*  brow8  = (uchar*)(ws + Ss + cvB);            // aliases h1 (+2MB <= 28MB)
    int2*   csr    = (int2*)(ws + Ss + Sh);
    int*    rowptr = (int*)(ws + Ss + Sh + csrB);
    char*   meta   = ws + Ss + Sh + csrB + rpB;
    int*    bbase  = (int*)meta;                          // 513 ints
    int*    colsum = (int*)(meta + 2560);                 // 512 ints
    ushort* Wt2    = (ushort*)(meta + 5120);              // 16 KB
    int*    partial= (int*)(meta + 5120 + 16384 + 512);   // BB*MAXB ints (~2MB)

    // 1. per-binblock hist + gemm1 + Wt2 prep
    histgemm<<<BB + gblocks + 32, 256, 0, stream>>>(row, partial, E, BB,
                                                    emb_node, emb_attri, NN,
                                                    W1, sup, N, W2, Wt2, gblocks);
    // 2a/2b. scans
    scanA<<<MAXB, 256, 0, stream>>>(partial, colsum, BB);
    scanB<<<1, 256, 0, stream>>>(colsum, bbase, rowptr, N, E);
    // 3. bin: LDS counting sort, deterministic writes
    bin_kernel<<<BB, 256, 0, stream>>>(row, col, vals, bbase, partial,
                                       brow8, bcolval, E);
    // 4. per-bucket row sort -> rowptr + csr
    final_scatter<<<nbuckets, 512, 0, stream>>>(bbase, brow8, bcolval, rowptr, csr, N);
    // 5. layer-1 aggregation
    agg_kernel128<<<ablocks, 256, 0, stream>>>(sup, rowptr, csr, b1, h1, N);
    // 6. layer-2 GEMM
    gemm_mfma64<<<gblocks, 256, 0, stream>>>(h1, Wt2, sup, N);
    // 7. layer-2 aggregation (4 rows/wave, quarter per row)
    agg_kernel64<<<(N + 15) / 16, 256, 0, stream>>>(sup, rowptr, csr, b2, (float*)d_out, N);
}